// Round 3
// baseline (213.405 us; speedup 1.0000x reference)
//
#include <hip/hip_runtime.h>
#include <cstring>
#include <cstdint>
#include <cmath>

// Problem constants (fixed by the reference): x is (64, 3, 384, 384) f32.
#define B_IMG 64
#define C_IMG 3
#define H_IMG 384
#define W_IMG 384
#define PLANE (H_IMG * W_IMG)                    // 147456
#define N_TOT (B_IMG * C_IMG * PLANE)            // 28,311,552
#define N4    (N_TOT / 4)                        // 7,077,888
#define F_PER_BLOCK 4096                         // floats per block (divides PLANE: 147456/4096=36)
#define BLOCKS (N_TOT / F_PER_BLOCK)             // 6912

typedef float nfloat4 __attribute__((ext_vector_type(4)));  // native vec for nontemporal store

struct Rect { int t, b, l, r; };        // rows [t,b), cols [l,r); empty if t==b
struct Params { Rect rc[B_IMG]; };      // 1 KB, passed by value as kernarg

__host__ __device__ inline uint32_t rotl32(uint32_t x, uint32_t r) {
  return (x << r) | (x >> (32u - r));
}

// JAX threefry2x32 (20 rounds), bit-exact integer hash.
__host__ __device__ inline void tf2x32(uint32_t k0, uint32_t k1,
                                       uint32_t x0, uint32_t x1,
                                       uint32_t& o0, uint32_t& o1) {
  const uint32_t ks2 = k0 ^ k1 ^ 0x1BD11BDAu;
  x0 += k0; x1 += k1;
  x0 += x1; x1 = rotl32(x1, 13); x1 ^= x0;
  x0 += x1; x1 = rotl32(x1, 15); x1 ^= x0;
  x0 += x1; x1 = rotl32(x1, 26); x1 ^= x0;
  x0 += x1; x1 = rotl32(x1,  6); x1 ^= x0;
  x0 += k1; x1 += ks2 + 1u;
  x0 += x1; x1 = rotl32(x1, 17); x1 ^= x0;
  x0 += x1; x1 = rotl32(x1, 29); x1 ^= x0;
  x0 += x1; x1 = rotl32(x1, 16); x1 ^= x0;
  x0 += x1; x1 = rotl32(x1, 24); x1 ^= x0;
  x0 += ks2; x1 += k0 + 2u;
  x0 += x1; x1 = rotl32(x1, 13); x1 ^= x0;
  x0 += x1; x1 = rotl32(x1, 15); x1 ^= x0;
  x0 += x1; x1 = rotl32(x1, 26); x1 ^= x0;
  x0 += x1; x1 = rotl32(x1,  6); x1 ^= x0;
  x0 += k0; x1 += k1 + 3u;
  x0 += x1; x1 = rotl32(x1, 17); x1 ^= x0;
  x0 += x1; x1 = rotl32(x1, 29); x1 ^= x0;
  x0 += x1; x1 = rotl32(x1, 16); x1 ^= x0;
  x0 += x1; x1 = rotl32(x1, 24); x1 ^= x0;
  x0 += k1; x1 += ks2 + 4u;
  x0 += x1; x1 = rotl32(x1, 13); x1 ^= x0;
  x0 += x1; x1 = rotl32(x1, 15); x1 ^= x0;
  x0 += x1; x1 = rotl32(x1, 26); x1 ^= x0;
  x0 += x1; x1 = rotl32(x1,  6); x1 ^= x0;
  x0 += ks2; x1 += k0 + 5u;
  o0 = x0; o1 = x1;
}

// bits -> float in [0,1): bitcast((bits>>9)|0x3f800000) - 1.0f  (exact)
__host__ __device__ inline float unit_from_bits(uint32_t bits) {
  uint32_t fb = (bits >> 9) | 0x3f800000u;
  float f;
#ifdef __HIP_DEVICE_COMPILE__
  f = __uint_as_float(fb);
#else
  memcpy(&f, &fb, 4);
#endif
  return f - 1.0f;
}

// JAX partitionable-mode random bits for element idx: o0 ^ o1 of tf(key,(0,idx)).
__host__ __device__ inline uint32_t rb_partitionable(uint32_t k0, uint32_t k1, uint32_t idx) {
  uint32_t o0, o1;
  tf2x32(k0, k1, 0u, idx, o0, o1);
  return o0 ^ o1;
}

// sqrt(2) * erfinv(u) matching XLA's f32 ErfInv expansion (Giles polynomial).
// Strict f32 ops (no contraction) so the tail matches the reference.
__device__ inline float noise_val(uint32_t idx, uint32_t kn0, uint32_t kn1) {
  const float LO = -0x1.fffffep-1f;           // nextafter(-1,0)
  uint32_t bits = rb_partitionable(kn0, kn1, idx);
  float f = unit_from_bits(bits);              // [0,1), exact
  float u = __fadd_rn(__fmul_rn(f, 2.0f), LO);
  u = fmaxf(LO, u);
  float t  = __fmul_rn(u, u);
  float wv = -log1pf(-t);
  float p;
  if (wv < 5.0f) {
    float ww = __fadd_rn(wv, -2.5f);
    p = 2.81022636e-08f;
    p = __fadd_rn(__fmul_rn(p, ww),  3.43273939e-07f);
    p = __fadd_rn(__fmul_rn(p, ww), -3.5233877e-06f);
    p = __fadd_rn(__fmul_rn(p, ww), -4.39150654e-06f);
    p = __fadd_rn(__fmul_rn(p, ww),  0.00021858087f);
    p = __fadd_rn(__fmul_rn(p, ww), -0.00125372503f);
    p = __fadd_rn(__fmul_rn(p, ww), -0.00417768164f);
    p = __fadd_rn(__fmul_rn(p, ww),  0.246640727f);
    p = __fadd_rn(__fmul_rn(p, ww),  1.50140941f);
  } else {
    float ww = __fadd_rn(__fsqrt_rn(wv), -3.0f);
    p = -0.000200214257f;
    p = __fadd_rn(__fmul_rn(p, ww),  0.000100950558f);
    p = __fadd_rn(__fmul_rn(p, ww),  0.00134934322f);
    p = __fadd_rn(__fmul_rn(p, ww), -0.00367342844f);
    p = __fadd_rn(__fmul_rn(p, ww),  0.00573950773f);
    p = __fadd_rn(__fmul_rn(p, ww), -0.0076224613f);
    p = __fadd_rn(__fmul_rn(p, ww),  0.00943887047f);
    p = __fadd_rn(__fmul_rn(p, ww),  1.00167406f);
    p = __fadd_rn(__fmul_rn(p, ww),  2.83297682f);
  }
  float r = __fmul_rn(p, u);
  return __fmul_rn(1.41421356237f, r);        // np.float32(np.sqrt(2))
}

// Host-side: derive the 6 subkeys (fold-like split of key(42)) and the 64
// per-sample erase rectangles. Deterministic, identical every call.
static void compute_host_params(Params& P, uint32_t& kn0, uint32_t& kn1) {
#pragma clang fp contract(off)
  uint32_t keys[6][2];  // kp, ka, kr, kt, kl, kn
  for (uint32_t i = 0; i < 6; i++)
    tf2x32(0u, 42u, 0u, i, keys[i][0], keys[i][1]);
  kn0 = keys[5][0]; kn1 = keys[5][1];

  for (int b = 0; b < B_IMG; b++) {
    float u[5];
    for (int k = 0; k < 5; k++)
      u[k] = unit_from_bits(rb_partitionable(keys[k][0], keys[k][1], (uint32_t)b));

    float up = u[0];
    float da = 0.33f - 0.02f;
    float ua = u[1] * da;  ua = ua + 0.02f;  ua = fmaxf(0.02f, ua);
    float ta = ua * 147456.0f;
    float dr = 3.3f - 0.3f;
    float ur = u[2] * dr;  ur = ur + 0.3f;   ur = fmaxf(0.3f, ur);

    int he = (int)rintf(sqrtf(ta * ur));
    int we = (int)rintf(sqrtf(ta / ur));
    bool valid = (up <= 0.5f) && (he < H_IMG) && (we < W_IMG);

    int top  = (int)floorf(u[3] * (float)(H_IMG - he + 1));
    int left = (int)floorf(u[4] * (float)(W_IMG - we + 1));

    if (valid) { P.rc[b].t = top;  P.rc[b].b = top + he; P.rc[b].l = left; P.rc[b].r = left + we; }
    else       { P.rc[b].t = 0;    P.rc[b].b = 0;        P.rc[b].l = 0;    P.rc[b].r = 0; }
  }
}

// Each block: 4096 consecutive floats (1024 float4s) = exactly 1/36 of one
// (b,c) channel plane, so b/c/rect are block-uniform. Each thread: 4 float4s
// (64 B), all loads issued before any use -> 4x MLP vs R0.
__global__ __launch_bounds__(256) void erase_norm_kernel(
    const float* __restrict__ x, const float* __restrict__ mean,
    const float* __restrict__ stdv, float* __restrict__ out,
    Params P, uint32_t kn0, uint32_t kn1) {
  const int t = threadIdx.x;
  const int plane = blockIdx.x / (PLANE / F_PER_BLOCK);   // / 36
  const int c = plane % C_IMG;
  const int b = plane / C_IMG;

  const nfloat4* __restrict__ x4 = reinterpret_cast<const nfloat4*>(x);
  nfloat4* __restrict__ o4 = reinterpret_cast<nfloat4*>(out);

  int i4[4];
  nfloat4 v[4];
#pragma unroll
  for (int j = 0; j < 4; j++) {
    i4[j] = blockIdx.x * 1024 + j * 256 + t;
    v[j] = x4[i4[j]];                       // 4 independent loads in flight
  }

  const float m  = mean[c];
  const float rs = 1.0f / stdv[c];          // one divide per thread (was 4 full IEEE divides)
  const float nm = -m * rs;
  const Rect rc = P.rc[b];
  const int planeBase = plane * PLANE;

#pragma unroll
  for (int j = 0; j < 4; j++) {
    nfloat4 o;
    o.x = fmaf(v[j].x, rs, nm);
    o.y = fmaf(v[j].y, rs, nm);
    o.z = fmaf(v[j].z, rs, nm);
    o.w = fmaf(v[j].w, rs, nm);

    const int base = i4[j] * 4;
    const int rel  = base - planeBase;      // [0, 147456)
    const int h = rel / W_IMG;
    const int w = rel - h * W_IMG;
    if (h >= rc.t && h < rc.b && w < rc.r && (w + 3) >= rc.l) {
      if (w     >= rc.l && w     < rc.r) o.x = noise_val((uint32_t)(base + 0), kn0, kn1);
      if (w + 1 >= rc.l && w + 1 < rc.r) o.y = noise_val((uint32_t)(base + 1), kn0, kn1);
      if (w + 2 >= rc.l && w + 2 < rc.r) o.z = noise_val((uint32_t)(base + 2), kn0, kn1);
      if (w + 3 >= rc.l && w + 3 < rc.r) o.w = noise_val((uint32_t)(base + 3), kn0, kn1);
    }
    __builtin_nontemporal_store(o, &o4[i4[j]]);   // keep x resident in L3
  }
}

extern "C" void kernel_launch(void* const* d_in, const int* in_sizes, int n_in,
                              void* d_out, int out_size, void* d_ws, size_t ws_size,
                              hipStream_t stream) {
  const float* x    = (const float*)d_in[0];
  const float* mean = (const float*)d_in[1];
  const float* stdv = (const float*)d_in[2];
  float* out = (float*)d_out;

  Params P;
  uint32_t kn0, kn1;
  compute_host_params(P, kn0, kn1);

  erase_norm_kernel<<<BLOCKS, 256, 0, stream>>>(x, mean, stdv, out, P, kn0, kn1);
}

// Round 4
// 212.230 us; speedup vs baseline: 1.0055x; 1.0055x over previous
//
#include <hip/hip_runtime.h>
#include <cstring>
#include <cstdint>
#include <cmath>

// Problem constants (fixed by the reference): x is (64, 3, 384, 384) f32.
#define B_IMG 64
#define C_IMG 3
#define H_IMG 384
#define W_IMG 384
#define PLANE (H_IMG * W_IMG)                    // 147456
#define N_TOT (B_IMG * C_IMG * PLANE)            // 28,311,552
#define N4    (N_TOT / 4)                        // 7,077,888
#define F_PER_BLOCK 4096                         // floats per block (divides PLANE: 147456/4096=36)
#define BLOCKS (N_TOT / F_PER_BLOCK)             // 6912

struct Rect { int t, b, l, r; };        // rows [t,b), cols [l,r); empty if t==b
struct Params { Rect rc[B_IMG]; };      // 1 KB, passed by value as kernarg

__host__ __device__ inline uint32_t rotl32(uint32_t x, uint32_t r) {
  return (x << r) | (x >> (32u - r));
}

// JAX threefry2x32 (20 rounds), bit-exact integer hash.
__host__ __device__ inline void tf2x32(uint32_t k0, uint32_t k1,
                                       uint32_t x0, uint32_t x1,
                                       uint32_t& o0, uint32_t& o1) {
  const uint32_t ks2 = k0 ^ k1 ^ 0x1BD11BDAu;
  x0 += k0; x1 += k1;
  x0 += x1; x1 = rotl32(x1, 13); x1 ^= x0;
  x0 += x1; x1 = rotl32(x1, 15); x1 ^= x0;
  x0 += x1; x1 = rotl32(x1, 26); x1 ^= x0;
  x0 += x1; x1 = rotl32(x1,  6); x1 ^= x0;
  x0 += k1; x1 += ks2 + 1u;
  x0 += x1; x1 = rotl32(x1, 17); x1 ^= x0;
  x0 += x1; x1 = rotl32(x1, 29); x1 ^= x0;
  x0 += x1; x1 = rotl32(x1, 16); x1 ^= x0;
  x0 += x1; x1 = rotl32(x1, 24); x1 ^= x0;
  x0 += ks2; x1 += k0 + 2u;
  x0 += x1; x1 = rotl32(x1, 13); x1 ^= x0;
  x0 += x1; x1 = rotl32(x1, 15); x1 ^= x0;
  x0 += x1; x1 = rotl32(x1, 26); x1 ^= x0;
  x0 += x1; x1 = rotl32(x1,  6); x1 ^= x0;
  x0 += k0; x1 += k1 + 3u;
  x0 += x1; x1 = rotl32(x1, 17); x1 ^= x0;
  x0 += x1; x1 = rotl32(x1, 29); x1 ^= x0;
  x0 += x1; x1 = rotl32(x1, 16); x1 ^= x0;
  x0 += x1; x1 = rotl32(x1, 24); x1 ^= x0;
  x0 += k1; x1 += ks2 + 4u;
  x0 += x1; x1 = rotl32(x1, 13); x1 ^= x0;
  x0 += x1; x1 = rotl32(x1, 15); x1 ^= x0;
  x0 += x1; x1 = rotl32(x1, 26); x1 ^= x0;
  x0 += x1; x1 = rotl32(x1,  6); x1 ^= x0;
  x0 += ks2; x1 += k0 + 5u;
  o0 = x0; o1 = x1;
}

// bits -> float in [0,1): bitcast((bits>>9)|0x3f800000) - 1.0f  (exact)
__host__ __device__ inline float unit_from_bits(uint32_t bits) {
  uint32_t fb = (bits >> 9) | 0x3f800000u;
  float f;
#ifdef __HIP_DEVICE_COMPILE__
  f = __uint_as_float(fb);
#else
  memcpy(&f, &fb, 4);
#endif
  return f - 1.0f;
}

// JAX partitionable-mode random bits for element idx: o0 ^ o1 of tf(key,(0,idx)).
__host__ __device__ inline uint32_t rb_partitionable(uint32_t k0, uint32_t k1, uint32_t idx) {
  uint32_t o0, o1;
  tf2x32(k0, k1, 0u, idx, o0, o1);
  return o0 ^ o1;
}

// sqrt(2) * erfinv(u) matching XLA's f32 ErfInv expansion (Giles polynomial).
// Strict f32 ops (no contraction) so the tail matches the reference.
__device__ inline float noise_val(uint32_t idx, uint32_t kn0, uint32_t kn1) {
  const float LO = -0x1.fffffep-1f;           // nextafter(-1,0)
  uint32_t bits = rb_partitionable(kn0, kn1, idx);
  float f = unit_from_bits(bits);              // [0,1), exact
  float u = __fadd_rn(__fmul_rn(f, 2.0f), LO);
  u = fmaxf(LO, u);
  float t  = __fmul_rn(u, u);
  float wv = -log1pf(-t);
  float p;
  if (wv < 5.0f) {
    float ww = __fadd_rn(wv, -2.5f);
    p = 2.81022636e-08f;
    p = __fadd_rn(__fmul_rn(p, ww),  3.43273939e-07f);
    p = __fadd_rn(__fmul_rn(p, ww), -3.5233877e-06f);
    p = __fadd_rn(__fmul_rn(p, ww), -4.39150654e-06f);
    p = __fadd_rn(__fmul_rn(p, ww),  0.00021858087f);
    p = __fadd_rn(__fmul_rn(p, ww), -0.00125372503f);
    p = __fadd_rn(__fmul_rn(p, ww), -0.00417768164f);
    p = __fadd_rn(__fmul_rn(p, ww),  0.246640727f);
    p = __fadd_rn(__fmul_rn(p, ww),  1.50140941f);
  } else {
    float ww = __fadd_rn(__fsqrt_rn(wv), -3.0f);
    p = -0.000200214257f;
    p = __fadd_rn(__fmul_rn(p, ww),  0.000100950558f);
    p = __fadd_rn(__fmul_rn(p, ww),  0.00134934322f);
    p = __fadd_rn(__fmul_rn(p, ww), -0.00367342844f);
    p = __fadd_rn(__fmul_rn(p, ww),  0.00573950773f);
    p = __fadd_rn(__fmul_rn(p, ww), -0.0076224613f);
    p = __fadd_rn(__fmul_rn(p, ww),  0.00943887047f);
    p = __fadd_rn(__fmul_rn(p, ww),  1.00167406f);
    p = __fadd_rn(__fmul_rn(p, ww),  2.83297682f);
  }
  float r = __fmul_rn(p, u);
  return __fmul_rn(1.41421356237f, r);        // np.float32(np.sqrt(2))
}

// Host-side: derive the 6 subkeys (fold-like split of key(42)) and the 64
// per-sample erase rectangles. Deterministic, identical every call.
static void compute_host_params(Params& P, uint32_t& kn0, uint32_t& kn1) {
#pragma clang fp contract(off)
  uint32_t keys[6][2];  // kp, ka, kr, kt, kl, kn
  for (uint32_t i = 0; i < 6; i++)
    tf2x32(0u, 42u, 0u, i, keys[i][0], keys[i][1]);
  kn0 = keys[5][0]; kn1 = keys[5][1];

  for (int b = 0; b < B_IMG; b++) {
    float u[5];
    for (int k = 0; k < 5; k++)
      u[k] = unit_from_bits(rb_partitionable(keys[k][0], keys[k][1], (uint32_t)b));

    float up = u[0];
    float da = 0.33f - 0.02f;
    float ua = u[1] * da;  ua = ua + 0.02f;  ua = fmaxf(0.02f, ua);
    float ta = ua * 147456.0f;
    float dr = 3.3f - 0.3f;
    float ur = u[2] * dr;  ur = ur + 0.3f;   ur = fmaxf(0.3f, ur);

    int he = (int)rintf(sqrtf(ta * ur));
    int we = (int)rintf(sqrtf(ta / ur));
    bool valid = (up <= 0.5f) && (he < H_IMG) && (we < W_IMG);

    int top  = (int)floorf(u[3] * (float)(H_IMG - he + 1));
    int left = (int)floorf(u[4] * (float)(W_IMG - we + 1));

    if (valid) { P.rc[b].t = top;  P.rc[b].b = top + he; P.rc[b].l = left; P.rc[b].r = left + we; }
    else       { P.rc[b].t = 0;    P.rc[b].b = 0;        P.rc[b].l = 0;    P.rc[b].r = 0; }
  }
}

// Each block: 4096 consecutive floats (1024 float4s) = exactly 1/36 of one
// (b,c) channel plane, so b/c/rect are block-uniform. Each thread: 4 float4s
// (64 B), all loads issued before any use -> 4x MLP. Plain stores (R3's
// nontemporal stores regressed HBM write efficiency: 2.48 -> 2.08 TB/s).
__global__ __launch_bounds__(256) void erase_norm_kernel(
    const float* __restrict__ x, const float* __restrict__ mean,
    const float* __restrict__ stdv, float* __restrict__ out,
    Params P, uint32_t kn0, uint32_t kn1) {
  const int t = threadIdx.x;
  const int plane = blockIdx.x / (PLANE / F_PER_BLOCK);   // / 36
  const int c = plane % C_IMG;
  const int b = plane / C_IMG;

  const float4* __restrict__ x4 = reinterpret_cast<const float4*>(x);
  float4* __restrict__ o4 = reinterpret_cast<float4*>(out);

  int i4[4];
  float4 v[4];
#pragma unroll
  for (int j = 0; j < 4; j++) {
    i4[j] = blockIdx.x * 1024 + j * 256 + t;
    v[j] = x4[i4[j]];                       // 4 independent loads in flight
  }

  const float m  = mean[c];
  const float rs = 1.0f / stdv[c];          // one divide per thread (was 4 full IEEE divides)
  const float nm = -m * rs;
  const Rect rc = P.rc[b];
  const int planeBase = plane * PLANE;

#pragma unroll
  for (int j = 0; j < 4; j++) {
    float4 o;
    o.x = fmaf(v[j].x, rs, nm);
    o.y = fmaf(v[j].y, rs, nm);
    o.z = fmaf(v[j].z, rs, nm);
    o.w = fmaf(v[j].w, rs, nm);

    const int base = i4[j] * 4;
    const int rel  = base - planeBase;      // [0, 147456)
    const int h = rel / W_IMG;
    const int w = rel - h * W_IMG;
    if (h >= rc.t && h < rc.b && w < rc.r && (w + 3) >= rc.l) {
      if (w     >= rc.l && w     < rc.r) o.x = noise_val((uint32_t)(base + 0), kn0, kn1);
      if (w + 1 >= rc.l && w + 1 < rc.r) o.y = noise_val((uint32_t)(base + 1), kn0, kn1);
      if (w + 2 >= rc.l && w + 2 < rc.r) o.z = noise_val((uint32_t)(base + 2), kn0, kn1);
      if (w + 3 >= rc.l && w + 3 < rc.r) o.w = noise_val((uint32_t)(base + 3), kn0, kn1);
    }
    o4[i4[j]] = o;                          // plain store through L2
  }
}

extern "C" void kernel_launch(void* const* d_in, const int* in_sizes, int n_in,
                              void* d_out, int out_size, void* d_ws, size_t ws_size,
                              hipStream_t stream) {
  const float* x    = (const float*)d_in[0];
  const float* mean = (const float*)d_in[1];
  const float* stdv = (const float*)d_in[2];
  float* out = (float*)d_out;

  Params P;
  uint32_t kn0, kn1;
  compute_host_params(P, kn0, kn1);

  erase_norm_kernel<<<BLOCKS, 256, 0, stream>>>(x, mean, stdv, out, P, kn0, kn1);
}

// Round 5
// 202.606 us; speedup vs baseline: 1.0533x; 1.0475x over previous
//
#include <hip/hip_runtime.h>
#include <cstring>
#include <cstdint>
#include <cmath>

// Problem constants (fixed by the reference): x is (64, 3, 384, 384) f32.
#define B_IMG 64
#define C_IMG 3
#define H_IMG 384
#define W_IMG 384
#define PLANE (H_IMG * W_IMG)                    // 147456
#define N_TOT (B_IMG * C_IMG * PLANE)            // 28,311,552
#define N4    (N_TOT / 4)                        // 7,077,888

typedef float nfloat4 __attribute__((ext_vector_type(4)));  // native vec for nontemporal builtins

struct Rect { int t, b, l, r; };        // rows [t,b), cols [l,r); empty if t==b
struct Params { Rect rc[B_IMG]; };      // 1 KB, passed by value as kernarg

__host__ __device__ inline uint32_t rotl32(uint32_t x, uint32_t r) {
  return (x << r) | (x >> (32u - r));
}

// JAX threefry2x32 (20 rounds), bit-exact integer hash.
__host__ __device__ inline void tf2x32(uint32_t k0, uint32_t k1,
                                       uint32_t x0, uint32_t x1,
                                       uint32_t& o0, uint32_t& o1) {
  const uint32_t ks2 = k0 ^ k1 ^ 0x1BD11BDAu;
  x0 += k0; x1 += k1;
  x0 += x1; x1 = rotl32(x1, 13); x1 ^= x0;
  x0 += x1; x1 = rotl32(x1, 15); x1 ^= x0;
  x0 += x1; x1 = rotl32(x1, 26); x1 ^= x0;
  x0 += x1; x1 = rotl32(x1,  6); x1 ^= x0;
  x0 += k1; x1 += ks2 + 1u;
  x0 += x1; x1 = rotl32(x1, 17); x1 ^= x0;
  x0 += x1; x1 = rotl32(x1, 29); x1 ^= x0;
  x0 += x1; x1 = rotl32(x1, 16); x1 ^= x0;
  x0 += x1; x1 = rotl32(x1, 24); x1 ^= x0;
  x0 += ks2; x1 += k0 + 2u;
  x0 += x1; x1 = rotl32(x1, 13); x1 ^= x0;
  x0 += x1; x1 = rotl32(x1, 15); x1 ^= x0;
  x0 += x1; x1 = rotl32(x1, 26); x1 ^= x0;
  x0 += x1; x1 = rotl32(x1,  6); x1 ^= x0;
  x0 += k0; x1 += k1 + 3u;
  x0 += x1; x1 = rotl32(x1, 17); x1 ^= x0;
  x0 += x1; x1 = rotl32(x1, 29); x1 ^= x0;
  x0 += x1; x1 = rotl32(x1, 16); x1 ^= x0;
  x0 += x1; x1 = rotl32(x1, 24); x1 ^= x0;
  x0 += k1; x1 += ks2 + 4u;
  x0 += x1; x1 = rotl32(x1, 13); x1 ^= x0;
  x0 += x1; x1 = rotl32(x1, 15); x1 ^= x0;
  x0 += x1; x1 = rotl32(x1, 26); x1 ^= x0;
  x0 += x1; x1 = rotl32(x1,  6); x1 ^= x0;
  x0 += ks2; x1 += k0 + 5u;
  o0 = x0; o1 = x1;
}

// bits -> float in [0,1): bitcast((bits>>9)|0x3f800000) - 1.0f  (exact)
__host__ __device__ inline float unit_from_bits(uint32_t bits) {
  uint32_t fb = (bits >> 9) | 0x3f800000u;
  float f;
#ifdef __HIP_DEVICE_COMPILE__
  f = __uint_as_float(fb);
#else
  memcpy(&f, &fb, 4);
#endif
  return f - 1.0f;
}

// JAX partitionable-mode random bits for element idx: o0 ^ o1 of tf(key,(0,idx)).
__host__ __device__ inline uint32_t rb_partitionable(uint32_t k0, uint32_t k1, uint32_t idx) {
  uint32_t o0, o1;
  tf2x32(k0, k1, 0u, idx, o0, o1);
  return o0 ^ o1;
}

// sqrt(2) * erfinv(u) matching XLA's f32 ErfInv expansion (Giles polynomial).
// Strict f32 ops (no contraction) so the tail matches the reference.
__device__ inline float noise_val(uint32_t idx, uint32_t kn0, uint32_t kn1) {
  const float LO = -0x1.fffffep-1f;           // nextafter(-1,0)
  uint32_t bits = rb_partitionable(kn0, kn1, idx);
  float f = unit_from_bits(bits);              // [0,1), exact
  float u = __fadd_rn(__fmul_rn(f, 2.0f), LO);
  u = fmaxf(LO, u);
  float t  = __fmul_rn(u, u);
  float wv = -log1pf(-t);
  float p;
  if (wv < 5.0f) {
    float ww = __fadd_rn(wv, -2.5f);
    p = 2.81022636e-08f;
    p = __fadd_rn(__fmul_rn(p, ww),  3.43273939e-07f);
    p = __fadd_rn(__fmul_rn(p, ww), -3.5233877e-06f);
    p = __fadd_rn(__fmul_rn(p, ww), -4.39150654e-06f);
    p = __fadd_rn(__fmul_rn(p, ww),  0.00021858087f);
    p = __fadd_rn(__fmul_rn(p, ww), -0.00125372503f);
    p = __fadd_rn(__fmul_rn(p, ww), -0.00417768164f);
    p = __fadd_rn(__fmul_rn(p, ww),  0.246640727f);
    p = __fadd_rn(__fmul_rn(p, ww),  1.50140941f);
  } else {
    float ww = __fadd_rn(__fsqrt_rn(wv), -3.0f);
    p = -0.000200214257f;
    p = __fadd_rn(__fmul_rn(p, ww),  0.000100950558f);
    p = __fadd_rn(__fmul_rn(p, ww),  0.00134934322f);
    p = __fadd_rn(__fmul_rn(p, ww), -0.00367342844f);
    p = __fadd_rn(__fmul_rn(p, ww),  0.00573950773f);
    p = __fadd_rn(__fmul_rn(p, ww), -0.0076224613f);
    p = __fadd_rn(__fmul_rn(p, ww),  0.00943887047f);
    p = __fadd_rn(__fmul_rn(p, ww),  1.00167406f);
    p = __fadd_rn(__fmul_rn(p, ww),  2.83297682f);
  }
  float r = __fmul_rn(p, u);
  return __fmul_rn(1.41421356237f, r);        // np.float32(np.sqrt(2))
}

// Host-side: derive the 6 subkeys (fold-like split of key(42)) and the 64
// per-sample erase rectangles. Deterministic, identical every call.
static void compute_host_params(Params& P, uint32_t& kn0, uint32_t& kn1) {
#pragma clang fp contract(off)
  uint32_t keys[6][2];  // kp, ka, kr, kt, kl, kn
  for (uint32_t i = 0; i < 6; i++)
    tf2x32(0u, 42u, 0u, i, keys[i][0], keys[i][1]);
  kn0 = keys[5][0]; kn1 = keys[5][1];

  for (int b = 0; b < B_IMG; b++) {
    float u[5];
    for (int k = 0; k < 5; k++)
      u[k] = unit_from_bits(rb_partitionable(keys[k][0], keys[k][1], (uint32_t)b));

    float up = u[0];
    float da = 0.33f - 0.02f;
    float ua = u[1] * da;  ua = ua + 0.02f;  ua = fmaxf(0.02f, ua);
    float ta = ua * 147456.0f;
    float dr = 3.3f - 0.3f;
    float ur = u[2] * dr;  ur = ur + 0.3f;   ur = fmaxf(0.3f, ur);

    int he = (int)rintf(sqrtf(ta * ur));
    int we = (int)rintf(sqrtf(ta / ur));
    bool valid = (up <= 0.5f) && (he < H_IMG) && (we < W_IMG);

    int top  = (int)floorf(u[3] * (float)(H_IMG - he + 1));
    int left = (int)floorf(u[4] * (float)(W_IMG - we + 1));

    if (valid) { P.rc[b].t = top;  P.rc[b].b = top + he; P.rc[b].l = left; P.rc[b].r = left + we; }
    else       { P.rc[b].t = 0;    P.rc[b].b = 0;        P.rc[b].l = 0;    P.rc[b].r = 0; }
  }
}

// R0 structure (best measured memory shape: 27648 thin blocks, 1 float4/thread,
// ~65% occupancy) + rcp-FMA normalize (R3's confirmed VALU win) + nontemporal
// LOADS (x is single-use; evict-first frees L2 for the write stream).
// Stores stay plain (R4 showed nt stores were neutral-to-negative).
__global__ __launch_bounds__(256) void erase_norm_kernel(
    const float* __restrict__ x, const float* __restrict__ mean,
    const float* __restrict__ stdv, float* __restrict__ out,
    Params P, uint32_t kn0, uint32_t kn1) {
  const int i4 = blockIdx.x * 256 + threadIdx.x;
  const int base = i4 * 4;
  // 384 % 4 == 0 -> all 4 elements share (b,c,h)
  const int w    = base % W_IMG;
  const int rest = base / W_IMG;
  const int h  = rest % H_IMG;
  const int bc = rest / H_IMG;
  const int c  = bc % C_IMG;
  const int b  = bc / C_IMG;

  const nfloat4* __restrict__ x4 = reinterpret_cast<const nfloat4*>(x);
  nfloat4* __restrict__ o4 = reinterpret_cast<nfloat4*>(out);

  const nfloat4 v = __builtin_nontemporal_load(&x4[i4]);

  const float m  = mean[c];
  const float rs = 1.0f / stdv[c];          // one rcp (was 4 IEEE divides in R0)
  const float nm = -m * rs;

  nfloat4 o;
  o.x = fmaf(v.x, rs, nm);
  o.y = fmaf(v.y, rs, nm);
  o.z = fmaf(v.z, rs, nm);
  o.w = fmaf(v.w, rs, nm);

  const Rect rc = P.rc[b];
  if (h >= rc.t && h < rc.b && w < rc.r && (w + 3) >= rc.l) {
    if (w     >= rc.l && w     < rc.r) o.x = noise_val((uint32_t)(base + 0), kn0, kn1);
    if (w + 1 >= rc.l && w + 1 < rc.r) o.y = noise_val((uint32_t)(base + 1), kn0, kn1);
    if (w + 2 >= rc.l && w + 2 < rc.r) o.z = noise_val((uint32_t)(base + 2), kn0, kn1);
    if (w + 3 >= rc.l && w + 3 < rc.r) o.w = noise_val((uint32_t)(base + 3), kn0, kn1);
  }
  o4[i4] = o;                               // plain store through L2
}

extern "C" void kernel_launch(void* const* d_in, const int* in_sizes, int n_in,
                              void* d_out, int out_size, void* d_ws, size_t ws_size,
                              hipStream_t stream) {
  const float* x    = (const float*)d_in[0];
  const float* mean = (const float*)d_in[1];
  const float* stdv = (const float*)d_in[2];
  float* out = (float*)d_out;

  Params P;
  uint32_t kn0, kn1;
  compute_host_params(P, kn0, kn1);

  const int blocks = N4 / 256;   // 27648
  erase_norm_kernel<<<blocks, 256, 0, stream>>>(x, mean, stdv, out, P, kn0, kn1);
}

// Round 6
// 198.664 us; speedup vs baseline: 1.0742x; 1.0198x over previous
//
#include <hip/hip_runtime.h>
#include <cstring>
#include <cstdint>
#include <cmath>

// Problem constants (fixed by the reference): x is (64, 3, 384, 384) f32.
#define B_IMG 64
#define C_IMG 3
#define H_IMG 384
#define W_IMG 384
#define PLANE (H_IMG * W_IMG)                    // 147456
#define N_TOT (B_IMG * C_IMG * PLANE)            // 28,311,552
#define N4    (N_TOT / 4)                        // 7,077,888
#define V4_PER_BLOCK 512                          // float4s per block (2048 floats; 147456/2048 = 72)
#define BLOCKS (N4 / V4_PER_BLOCK)               // 13824

typedef float nfloat4 __attribute__((ext_vector_type(4)));  // native vec for nontemporal builtins

struct Rect { int t, b, l, r; };        // rows [t,b), cols [l,r); empty if t==b
struct Params { Rect rc[B_IMG]; };      // 1 KB, passed by value as kernarg

__host__ __device__ inline uint32_t rotl32(uint32_t x, uint32_t r) {
  return (x << r) | (x >> (32u - r));
}

// JAX threefry2x32 (20 rounds), bit-exact integer hash.
__host__ __device__ inline void tf2x32(uint32_t k0, uint32_t k1,
                                       uint32_t x0, uint32_t x1,
                                       uint32_t& o0, uint32_t& o1) {
  const uint32_t ks2 = k0 ^ k1 ^ 0x1BD11BDAu;
  x0 += k0; x1 += k1;
  x0 += x1; x1 = rotl32(x1, 13); x1 ^= x0;
  x0 += x1; x1 = rotl32(x1, 15); x1 ^= x0;
  x0 += x1; x1 = rotl32(x1, 26); x1 ^= x0;
  x0 += x1; x1 = rotl32(x1,  6); x1 ^= x0;
  x0 += k1; x1 += ks2 + 1u;
  x0 += x1; x1 = rotl32(x1, 17); x1 ^= x0;
  x0 += x1; x1 = rotl32(x1, 29); x1 ^= x0;
  x0 += x1; x1 = rotl32(x1, 16); x1 ^= x0;
  x0 += x1; x1 = rotl32(x1, 24); x1 ^= x0;
  x0 += ks2; x1 += k0 + 2u;
  x0 += x1; x1 = rotl32(x1, 13); x1 ^= x0;
  x0 += x1; x1 = rotl32(x1, 15); x1 ^= x0;
  x0 += x1; x1 = rotl32(x1, 26); x1 ^= x0;
  x0 += x1; x1 = rotl32(x1,  6); x1 ^= x0;
  x0 += k0; x1 += k1 + 3u;
  x0 += x1; x1 = rotl32(x1, 17); x1 ^= x0;
  x0 += x1; x1 = rotl32(x1, 29); x1 ^= x0;
  x0 += x1; x1 = rotl32(x1, 16); x1 ^= x0;
  x0 += x1; x1 = rotl32(x1, 24); x1 ^= x0;
  x0 += k1; x1 += ks2 + 4u;
  x0 += x1; x1 = rotl32(x1, 13); x1 ^= x0;
  x0 += x1; x1 = rotl32(x1, 15); x1 ^= x0;
  x0 += x1; x1 = rotl32(x1, 26); x1 ^= x0;
  x0 += x1; x1 = rotl32(x1,  6); x1 ^= x0;
  x0 += ks2; x1 += k0 + 5u;
  o0 = x0; o1 = x1;
}

// bits -> float in [0,1): bitcast((bits>>9)|0x3f800000) - 1.0f  (exact)
__host__ __device__ inline float unit_from_bits(uint32_t bits) {
  uint32_t fb = (bits >> 9) | 0x3f800000u;
  float f;
#ifdef __HIP_DEVICE_COMPILE__
  f = __uint_as_float(fb);
#else
  memcpy(&f, &fb, 4);
#endif
  return f - 1.0f;
}

// JAX partitionable-mode random bits for element idx: o0 ^ o1 of tf(key,(0,idx)).
__host__ __device__ inline uint32_t rb_partitionable(uint32_t k0, uint32_t k1, uint32_t idx) {
  uint32_t o0, o1;
  tf2x32(k0, k1, 0u, idx, o0, o1);
  return o0 ^ o1;
}

// sqrt(2) * erfinv(u) matching XLA's f32 ErfInv expansion (Giles polynomial).
// Strict f32 ops (no contraction) so the tail matches the reference.
__device__ inline float noise_val(uint32_t idx, uint32_t kn0, uint32_t kn1) {
  const float LO = -0x1.fffffep-1f;           // nextafter(-1,0)
  uint32_t bits = rb_partitionable(kn0, kn1, idx);
  float f = unit_from_bits(bits);              // [0,1), exact
  float u = __fadd_rn(__fmul_rn(f, 2.0f), LO);
  u = fmaxf(LO, u);
  float t  = __fmul_rn(u, u);
  float wv = -log1pf(-t);
  float p;
  if (wv < 5.0f) {
    float ww = __fadd_rn(wv, -2.5f);
    p = 2.81022636e-08f;
    p = __fadd_rn(__fmul_rn(p, ww),  3.43273939e-07f);
    p = __fadd_rn(__fmul_rn(p, ww), -3.5233877e-06f);
    p = __fadd_rn(__fmul_rn(p, ww), -4.39150654e-06f);
    p = __fadd_rn(__fmul_rn(p, ww),  0.00021858087f);
    p = __fadd_rn(__fmul_rn(p, ww), -0.00125372503f);
    p = __fadd_rn(__fmul_rn(p, ww), -0.00417768164f);
    p = __fadd_rn(__fmul_rn(p, ww),  0.246640727f);
    p = __fadd_rn(__fmul_rn(p, ww),  1.50140941f);
  } else {
    float ww = __fadd_rn(__fsqrt_rn(wv), -3.0f);
    p = -0.000200214257f;
    p = __fadd_rn(__fmul_rn(p, ww),  0.000100950558f);
    p = __fadd_rn(__fmul_rn(p, ww),  0.00134934322f);
    p = __fadd_rn(__fmul_rn(p, ww), -0.00367342844f);
    p = __fadd_rn(__fmul_rn(p, ww),  0.00573950773f);
    p = __fadd_rn(__fmul_rn(p, ww), -0.0076224613f);
    p = __fadd_rn(__fmul_rn(p, ww),  0.00943887047f);
    p = __fadd_rn(__fmul_rn(p, ww),  1.00167406f);
    p = __fadd_rn(__fmul_rn(p, ww),  2.83297682f);
  }
  float r = __fmul_rn(p, u);
  return __fmul_rn(1.41421356237f, r);        // np.float32(np.sqrt(2))
}

// Host-side: derive the 6 subkeys (fold-like split of key(42)) and the 64
// per-sample erase rectangles. Deterministic, identical every call.
static void compute_host_params(Params& P, uint32_t& kn0, uint32_t& kn1) {
#pragma clang fp contract(off)
  uint32_t keys[6][2];  // kp, ka, kr, kt, kl, kn
  for (uint32_t i = 0; i < 6; i++)
    tf2x32(0u, 42u, 0u, i, keys[i][0], keys[i][1]);
  kn0 = keys[5][0]; kn1 = keys[5][1];

  for (int b = 0; b < B_IMG; b++) {
    float u[5];
    for (int k = 0; k < 5; k++)
      u[k] = unit_from_bits(rb_partitionable(keys[k][0], keys[k][1], (uint32_t)b));

    float up = u[0];
    float da = 0.33f - 0.02f;
    float ua = u[1] * da;  ua = ua + 0.02f;  ua = fmaxf(0.02f, ua);
    float ta = ua * 147456.0f;
    float dr = 3.3f - 0.3f;
    float ur = u[2] * dr;  ur = ur + 0.3f;   ur = fmaxf(0.3f, ur);

    int he = (int)rintf(sqrtf(ta * ur));
    int we = (int)rintf(sqrtf(ta / ur));
    bool valid = (up <= 0.5f) && (he < H_IMG) && (we < W_IMG);

    int top  = (int)floorf(u[3] * (float)(H_IMG - he + 1));
    int left = (int)floorf(u[4] * (float)(W_IMG - we + 1));

    if (valid) { P.rc[b].t = top;  P.rc[b].b = top + he; P.rc[b].l = left; P.rc[b].r = left + we; }
    else       { P.rc[b].t = 0;    P.rc[b].b = 0;        P.rc[b].l = 0;    P.rc[b].r = 0; }
  }
}

// MLP=2 variant of the R5 shape: each block covers 512 consecutive float4s
// (2048 floats, exactly 1/72 of a channel plane -> plane/c/b block-uniform);
// each thread loads 2 float4s (t and t+256), both issued before any use.
// 13824 blocks. nt loads (single-use x), rcp-FMA normalize, plain stores.
__global__ __launch_bounds__(256) void erase_norm_kernel(
    const float* __restrict__ x, const float* __restrict__ mean,
    const float* __restrict__ stdv, float* __restrict__ out,
    Params P, uint32_t kn0, uint32_t kn1) {
  const int t = threadIdx.x;
  const int plane = blockIdx.x / (PLANE / (V4_PER_BLOCK * 4));  // / 72, block-uniform
  const int c = plane % C_IMG;
  const int b = plane / C_IMG;

  const nfloat4* __restrict__ x4 = reinterpret_cast<const nfloat4*>(x);
  nfloat4* __restrict__ o4 = reinterpret_cast<nfloat4*>(out);

  const int i0 = blockIdx.x * V4_PER_BLOCK + t;
  const int i1 = i0 + 256;
  const nfloat4 v0 = __builtin_nontemporal_load(&x4[i0]);   // 2 independent
  const nfloat4 v1 = __builtin_nontemporal_load(&x4[i1]);   // loads in flight

  const float m  = mean[c];
  const float rs = 1.0f / stdv[c];
  const float nm = -m * rs;
  const Rect rc = P.rc[b];
  const int planeBase = plane * PLANE;

  nfloat4 vv[2] = {v0, v1};
  int idx4[2] = {i0, i1};
#pragma unroll
  for (int j = 0; j < 2; j++) {
    nfloat4 o;
    o.x = fmaf(vv[j].x, rs, nm);
    o.y = fmaf(vv[j].y, rs, nm);
    o.z = fmaf(vv[j].z, rs, nm);
    o.w = fmaf(vv[j].w, rs, nm);

    const int base = idx4[j] * 4;
    const int rel  = base - planeBase;      // [0, 147456)
    const int h = rel / W_IMG;
    const int w = rel - h * W_IMG;
    if (h >= rc.t && h < rc.b && w < rc.r && (w + 3) >= rc.l) {
      if (w     >= rc.l && w     < rc.r) o.x = noise_val((uint32_t)(base + 0), kn0, kn1);
      if (w + 1 >= rc.l && w + 1 < rc.r) o.y = noise_val((uint32_t)(base + 1), kn0, kn1);
      if (w + 2 >= rc.l && w + 2 < rc.r) o.z = noise_val((uint32_t)(base + 2), kn0, kn1);
      if (w + 3 >= rc.l && w + 3 < rc.r) o.w = noise_val((uint32_t)(base + 3), kn0, kn1);
    }
    o4[idx4[j]] = o;                        // plain store through L2
  }
}

extern "C" void kernel_launch(void* const* d_in, const int* in_sizes, int n_in,
                              void* d_out, int out_size, void* d_ws, size_t ws_size,
                              hipStream_t stream) {
  const float* x    = (const float*)d_in[0];
  const float* mean = (const float*)d_in[1];
  const float* stdv = (const float*)d_in[2];
  float* out = (float*)d_out;

  Params P;
  uint32_t kn0, kn1;
  compute_host_params(P, kn0, kn1);

  erase_norm_kernel<<<BLOCKS, 256, 0, stream>>>(x, mean, stdv, out, P, kn0, kn1);
}